// Round 8
// baseline (83.730 us; speedup 1.0000x reference)
//
#include <hip/hip_runtime.h>

#define NBINS   1024
#define CAPC    4096
#define TARGETC 256
#define DET     100
#define XCLIP   4.135166556742356f
#define ROWSW   8      // rows per wave-chunk
#define BUFF4   192    // float4 slots per buffer (3 x 64)

__device__ inline float scalar_to_float(const int* p) {
  int v = *p;
  return (v >= 0 && v < (1 << 20)) ? (float)v : __int_as_float(v);
}

struct Box { float x1, y1, x2, y2; };

__device__ inline Box decode_clip(float4 r, float4 p, float W, float H) {
  float w = p.z - p.x, h = p.w - p.y;
  float cx = p.x + 0.5f * w, cy = p.y + 0.5f * h;
  float dx = r.x / 10.f, dy = r.y / 10.f;
  float dw = fminf(r.z / 5.f, XCLIP), dh = fminf(r.w / 5.f, XCLIP);
  float pcx = dx * w + cx, pcy = dy * h + cy;
  float pw = __expf(dw) * w, ph = __expf(dh) * h;
  Box b;
  b.x1 = fminf(fmaxf(pcx - 0.5f * pw, 0.f), W);
  b.y1 = fminf(fmaxf(pcy - 0.5f * ph, 0.f), H);
  b.x2 = fminf(fmaxf(pcx + 0.5f * pw, 0.f), W);
  b.y2 = fminf(fmaxf(pcy + 0.5f * ph, 0.f), H);
  return b;
}

__device__ inline float iou_f(const Box& a, const Box& b) {
  float area1 = (a.x2 - a.x1) * (a.y2 - a.y1);
  float area2 = (b.x2 - b.x1) * (b.y2 - b.y1);
  float lx = fmaxf(a.x1, b.x1), ly = fmaxf(a.y1, b.y1);
  float rx = fminf(a.x2, b.x2), ry = fminf(a.y2, b.y2);
  float w = fmaxf(rx - lx, 0.f), h = fmaxf(ry - ly, 0.f);
  float inter = w * h;
  return inter / (area1 + area2 - inter);
}

// K0: zero hist + counter.
__global__ __launch_bounds__(256) void k0_zero(unsigned int* __restrict__ hist) {
  int t = blockIdx.x * 256 + threadIdx.x;
  if (t < NBINS + 16) hist[t] = 0u;
}

// K1 v8: wave-autonomous streaming. Each wave owns its chunk stream and a
// private double-buffered LDS slice filled by global_load_lds DMA. Counted
// vmcnt(3) waits only for the PREVIOUS buffer's loads; the just-issued 3
// stay in flight across compute. No block barriers in the hot loop.
__global__ __launch_bounds__(256) void k1_score(
    const float* __restrict__ logits, const float* __restrict__ reg,
    const float* __restrict__ prop, const int* __restrict__ ph,
    const int* __restrict__ pw, float* __restrict__ scores,
    int* __restrict__ labels, unsigned int* __restrict__ hist, int N) {
  __shared__ float4 buf[4][2][BUFF4];     // 24576 B
  __shared__ unsigned int lh[NBINS];      // 4096 B
  const int t = threadIdx.x, wv = t >> 6, lane = t & 63;
  for (int i = t; i < NBINS; i += 256) lh[i] = 0u;
  __syncthreads();
  const float W = scalar_to_float(pw), H = scalar_to_float(ph);
  const int nchunks = (N + ROWSW - 1) / ROWSW;
  const int gw = blockIdx.x * 4 + wv, GW = gridDim.x * 4;

  auto stage = [&](int cc, int b) {
    const int rows = min(ROWSW, N - cc * ROWSW);
    const int nf = rows * 91, nf4 = nf >> 2;
    const float4* s4 = (const float4*)(logits + (size_t)cc * ROWSW * 91);
    float4* dst = &buf[wv][b][0];
    #pragma unroll
    for (int k = 0; k < 3; ++k) {
      int b4 = k << 6;
      if (b4 < nf4) {
        int g = b4 + lane;
        if (g > nf4 - 1) g = nf4 - 1;     // clamped dups land in slot pad
        __builtin_amdgcn_global_load_lds(
            (const __attribute__((address_space(1))) void*)(s4 + g),
            (__attribute__((address_space(3))) void*)(dst + b4),
            16, 0, 0);
      }
    }
    for (int i = (nf4 << 2) + lane; i < nf; i += 64)   // generic-N tail only
      ((float*)dst)[i] = logits[(size_t)cc * ROWSW * 91 + i];
  };

  int c = gw;
  int cur = 0;
  if (c < nchunks) stage(c, 0);
  while (c < nchunks) {
    const int cn = c + GW;
    if (cn < nchunks) {
      stage(cn, cur ^ 1);
      asm volatile("s_waitcnt vmcnt(3) lgkmcnt(0)" ::: "memory");
    } else {
      asm volatile("s_waitcnt vmcnt(0) lgkmcnt(0)" ::: "memory");
    }
    __builtin_amdgcn_sched_barrier(0);
    const int rows = min(ROWSW, N - c * ROWSW);
    const int r = lane >> 3, s = lane & 7;
    if (r < rows) {
      const float* rowp = (const float*)&buf[wv][cur][0] + r * 91;
      float mv = -3.402823466e38f; int mi = 1 << 20;
      float e0 = 0.f, e1 = 0.f;
      #pragma unroll
      for (int k = 0; k < 12; ++k) {
        int j = s + (k << 3);
        if (j < 91) {
          float v = rowp[j];
          float ex = __expf(v);
          if (k & 1) e1 += ex; else e0 += ex;
          if (v > mv) { mv = v; mi = j; }
        }
      }
      float e = e0 + e1;
      #pragma unroll
      for (int m = 1; m <= 4; m <<= 1) {
        float ov = __shfl_xor(mv, m, 64);
        int   oi = __shfl_xor(mi, m, 64);
        float oe = __shfl_xor(e, m, 64);
        e += oe;
        if (ov > mv || (ov == mv && oi < mi)) { mv = ov; mi = oi; }
      }
      if (s == 0) {
        float top1 = __expf(mv) / e;
        const int row = c * ROWSW + r;
        float4 rg = ((const float4*)reg)[row];
        float4 pp = ((const float4*)prop)[row];
        Box b = decode_clip(rg, pp, W, H);
        bool valid = (top1 > 0.05f) && ((b.x2 - b.x1) >= 0.01f) && ((b.y2 - b.y1) >= 0.01f);
        float sc = valid ? top1 : -1.f;
        scores[row] = sc;
        labels[row] = mi;
        if (sc > 0.f) {
          int bin = (int)(sc * (float)NBINS);
          if (bin > NBINS - 1) bin = NBINS - 1;
          atomicAdd(&lh[bin], 1u);
        }
      }
    }
    cur ^= 1;
    c = cn;
  }
  __syncthreads();
  for (int i = t; i < NBINS; i += 256) {
    unsigned int cu = lh[i];
    if (cu) atomicAdd(&hist[i], cu);
  }
}

// K2: wave-shuffle suffix scan (2 barriers), then compaction.
__global__ __launch_bounds__(1024) void k2_compact(
    const float* __restrict__ scores, const unsigned int* __restrict__ hist,
    unsigned long long* __restrict__ cand, unsigned int* __restrict__ counter, int N) {
  __shared__ unsigned int wsum[16];
  __shared__ unsigned int wtail[16];
  __shared__ int bstar;
  const int t = threadIdx.x;
  const int lane = t & 63, w = t >> 6;
  const unsigned int h0 = hist[t];
  unsigned int v = h0;
  #pragma unroll
  for (int m = 1; m < 64; m <<= 1) {
    unsigned int o = __shfl_down(v, m, 64);
    if (lane + m < 64) v += o;
  }
  if (lane == 0) wsum[w] = v;
  if (t == 0) bstar = 0;
  __syncthreads();
  if (w == 0) {
    unsigned int u = (lane < 16) ? wsum[lane] : 0u;
    unsigned int inc = u;
    #pragma unroll
    for (int m = 1; m < 16; m <<= 1) {
      unsigned int o = __shfl_down(inc, m, 64);
      if (lane + m < 16) inc += o;
    }
    if (lane < 16) wtail[lane] = inc - u;
  }
  __syncthreads();
  unsigned int St = v + wtail[w];
  unsigned int St1 = St - h0;
  if (St >= TARGETC && St1 < TARGETC) {
    int b = t;
    if (St > CAPC) b = t + 1;
    if (b > NBINS - 1) b = NBINS - 1;
    bstar = b;
  }
  __syncthreads();
  const int bs = bstar;
  for (int i = blockIdx.x * blockDim.x + t; i < N; i += gridDim.x * blockDim.x) {
    float sc = scores[i];
    if (sc > 0.f) {
      int bin = (int)(sc * (float)NBINS);
      if (bin > NBINS - 1) bin = NBINS - 1;
      if (bin >= bs) {
        unsigned int pos = atomicAdd(counter, 1u);
        if (pos < CAPC) {
          unsigned long long key =
              ((unsigned long long)__float_as_uint(sc) << 32) |
              (unsigned long long)(0xFFFFFFFFu - (unsigned int)i);
          cand[pos] = key;
        }
      }
    }
  }
}

// K3: single block. bitonic sort over next-pow2(count), chunked greedy NMS, output.
__global__ __launch_bounds__(1024) void k3_nms(
    const unsigned long long* __restrict__ cand, const unsigned int* __restrict__ counter,
    const float* __restrict__ reg, const float* __restrict__ prop,
    const int* __restrict__ labels, const int* __restrict__ ph,
    const int* __restrict__ pw, float* __restrict__ out) {
  __shared__ unsigned long long keys[CAPC];
  __shared__ Box kbox[DET];
  __shared__ int klab[DET];
  __shared__ float kscore[DET];
  __shared__ Box cbox[64];
  __shared__ int clab[64];
  __shared__ float cscore[64];
  __shared__ unsigned int supk[64];
  __shared__ unsigned int rowm[64][2];
  __shared__ int nkept;
  const int t = threadIdx.x;
  unsigned int cnt_u = *counter;
  int count = (cnt_u < (unsigned int)CAPC) ? (int)cnt_u : CAPC;
  int P = 1;
  while (P < count) P <<= 1;
  if (P < 2) P = 2;
  for (int i = t; i < P; i += 1024) keys[i] = (i < count) ? cand[i] : 0ULL;
  if (t == 0) nkept = 0;
  __syncthreads();
  for (int k = 2; k <= P; k <<= 1) {
    for (int j = k >> 1; j > 0; j >>= 1) {
      for (int i = t; i < P; i += 1024) {
        int ixj = i ^ j;
        if (ixj > i) {
          unsigned long long a = keys[i], b = keys[ixj];
          bool sw = ((i & k) == 0) ? (a < b) : (a > b);
          if (sw) { keys[i] = b; keys[ixj] = a; }
        }
      }
      __syncthreads();
    }
  }
  const float W = scalar_to_float(pw), H = scalar_to_float(ph);
  for (int base = 0; base < count && nkept < DET; base += 64) {
    int nc = count - base; if (nc > 64) nc = 64;
    if (t < 64) { supk[t] = 0u; rowm[t][0] = 0u; rowm[t][1] = 0u; }
    if (t < nc) {
      unsigned long long key = keys[base + t];
      int row = (int)(0xFFFFFFFFu - (unsigned int)(key & 0xFFFFFFFFULL));
      cscore[t] = __uint_as_float((unsigned int)(key >> 32));
      clab[t] = labels[row];
      float4 r = ((const float4*)reg)[row];
      float4 p = ((const float4*)prop)[row];
      cbox[t] = decode_clip(r, p, W, H);
    }
    __syncthreads();
    int nk = nkept;
    {
      int c = t >> 4, kk = t & 15;
      if (c < nc) {
        unsigned int hit = 0u;
        for (int j = kk; j < nk; j += 16) {
          if (clab[c] == klab[j] && iou_f(cbox[c], kbox[j]) > 0.5f) { hit = 1u; break; }
        }
        if (hit) atomicOr(&supk[c], 1u);
      }
    }
    for (int p4 = t; p4 < 64 * 64; p4 += 1024) {
      int a = p4 >> 6, b = p4 & 63;
      if (a < b && b < nc) {
        if (clab[a] == clab[b] && iou_f(cbox[a], cbox[b]) > 0.5f)
          atomicOr(&rowm[a][b >> 5], 1u << (b & 31));
      }
    }
    __syncthreads();
    if (t == 0) {
      unsigned int s0 = 0u, s1 = 0u;
      int nkl = nkept;
      for (int j = 0; j < nc && nkl < DET; ++j) {
        unsigned int bit = (j < 32) ? ((s0 >> j) & 1u) : ((s1 >> (j - 32)) & 1u);
        if (!supk[j] && !bit) {
          kbox[nkl] = cbox[j];
          klab[nkl] = clab[j];
          kscore[nkl] = cscore[j];
          ++nkl;
          s0 |= rowm[j][0];
          s1 |= rowm[j][1];
        }
      }
      nkept = nkl;
    }
    __syncthreads();
  }
  int nk = nkept;
  if (t < DET) {
    bool v = t < nk;
    Box b = v ? kbox[t] : Box{0.f, 0.f, 0.f, 0.f};
    out[t * 4 + 0] = b.x1;
    out[t * 4 + 1] = b.y1;
    out[t * 4 + 2] = b.x2;
    out[t * 4 + 3] = b.y2;
    out[400 + t] = v ? kscore[t] : 0.f;
    out[500 + t] = v ? (float)klab[t] : -1.f;
  }
}

extern "C" void kernel_launch(void* const* d_in, const int* in_sizes, int n_in,
                              void* d_out, int out_size, void* d_ws, size_t ws_size,
                              hipStream_t stream) {
  const float* logits = (const float*)d_in[0];
  const float* reg    = (const float*)d_in[1];
  const float* prop   = (const float*)d_in[2];
  const int*   ph     = (const int*)d_in[3];
  const int*   pw     = (const int*)d_in[4];
  float* out = (float*)d_out;

  const int N = in_sizes[1] / 4;

  char* ws = (char*)d_ws;
  float* scores = (float*)ws;                                  // N f32
  int* labels   = (int*)(ws + (size_t)N * 4);                  // N i32
  size_t off = (size_t)N * 8;
  off = (off + 255) & ~(size_t)255;
  unsigned int* hist = (unsigned int*)(ws + off);              // NBINS u32
  unsigned int* counter = hist + NBINS;                        // 1 u32
  unsigned long long* cand = (unsigned long long*)(ws + off + NBINS * 4 + 64); // CAPC u64

  k0_zero<<<(NBINS + 16 + 255) / 256, 256, 0, stream>>>(hist);
  k1_score<<<1280, 256, 0, stream>>>(logits, reg, prop, ph, pw, scores, labels, hist, N);
  k2_compact<<<256, 1024, 0, stream>>>(scores, hist, cand, counter, N);
  k3_nms<<<1, 1024, 0, stream>>>(cand, counter, reg, prop, labels, ph, pw, out);
}

// Round 9
// 79.664 us; speedup vs baseline: 1.0510x; 1.0510x over previous
//
#include <hip/hip_runtime.h>

#define NBINS   1024
#define CAPC    4096
#define TARGETC 256
#define DET     100
#define XCLIP   4.135166556742356f

__device__ inline float scalar_to_float(const int* p) {
  int v = *p;
  return (v >= 0 && v < (1 << 20)) ? (float)v : __int_as_float(v);
}

struct Box { float x1, y1, x2, y2; };

__device__ inline Box decode_clip(float4 r, float4 p, float W, float H) {
  float w = p.z - p.x, h = p.w - p.y;
  float cx = p.x + 0.5f * w, cy = p.y + 0.5f * h;
  float dx = r.x / 10.f, dy = r.y / 10.f;
  float dw = fminf(r.z / 5.f, XCLIP), dh = fminf(r.w / 5.f, XCLIP);
  float pcx = dx * w + cx, pcy = dy * h + cy;
  float pw = __expf(dw) * w, ph = __expf(dh) * h;
  Box b;
  b.x1 = fminf(fmaxf(pcx - 0.5f * pw, 0.f), W);
  b.y1 = fminf(fmaxf(pcy - 0.5f * ph, 0.f), H);
  b.x2 = fminf(fmaxf(pcx + 0.5f * pw, 0.f), W);
  b.y2 = fminf(fmaxf(pcy + 0.5f * ph, 0.f), H);
  return b;
}

__device__ inline float iou_f(const Box& a, const Box& b) {
  float area1 = (a.x2 - a.x1) * (a.y2 - a.y1);
  float area2 = (b.x2 - b.x1) * (b.y2 - b.y1);
  float lx = fmaxf(a.x1, b.x1), ly = fmaxf(a.y1, b.y1);
  float rx = fminf(a.x2, b.x2), ry = fminf(a.y2, b.y2);
  float w = fmaxf(rx - lx, 0.f), h = fmaxf(ry - ly, 0.f);
  float inter = w * h;
  return inter / (area1 + area2 - inter);
}

// K0: zero hist + counter.
__global__ __launch_bounds__(256) void k0_zero(unsigned int* __restrict__ hist) {
  int t = blockIdx.x * 256 + threadIdx.x;
  if (t < NBINS + 16) hist[t] = 0u;
}

// K1 v9: thread-per-row direct gather. Lane owns its row: 24 aligned float4
// loads (row start rounded down to a 16B boundary, per-element predication),
// single-pass dual-chain max/argmax + exp-sum in registers. No LDS tile, no
// staging, no barriers in the body, no shuffles. Hist flush identical to R8.
__global__ __launch_bounds__(256) void k1_score(
    const float* __restrict__ logits, const float* __restrict__ reg,
    const float* __restrict__ prop, const int* __restrict__ ph,
    const int* __restrict__ pw, float* __restrict__ scores,
    int* __restrict__ labels, unsigned int* __restrict__ hist, int N) {
  __shared__ unsigned int lh[NBINS];
  const int t = threadIdx.x;
  for (int i = t; i < NBINS; i += 256) lh[i] = 0u;
  __syncthreads();
  const float W = scalar_to_float(pw), H = scalar_to_float(ph);
  const int row = blockIdx.x * 256 + t;
  if (row < N) {
    float mv0 = -3.402823466e38f, mv1 = -3.402823466e38f;
    int   mi0 = 1 << 20,          mi1 = 1 << 20;
    float e0 = 0.f, e1 = 0.f;
    if (row < N - 1) {
      const size_t a = (size_t)row * 91;
      const float4* b4 = (const float4*)(logits + (a & ~(size_t)3));
      const int shift = (int)(a & 3);
      #pragma unroll
      for (int j = 0; j < 24; ++j) {
        float4 v4 = b4[j];
        {
          int idx = 4 * j + 0 - shift;
          bool ok = (idx >= 0) & (idx < 91);
          float ex = __expf(v4.x);
          e0 += ok ? ex : 0.f;
          if (ok && v4.x > mv0) { mv0 = v4.x; mi0 = idx; }
        }
        {
          int idx = 4 * j + 1 - shift;
          bool ok = (idx >= 0) & (idx < 91);
          float ex = __expf(v4.y);
          e1 += ok ? ex : 0.f;
          if (ok && v4.y > mv1) { mv1 = v4.y; mi1 = idx; }
        }
        {
          int idx = 4 * j + 2 - shift;
          bool ok = (idx >= 0) & (idx < 91);
          float ex = __expf(v4.z);
          e0 += ok ? ex : 0.f;
          if (ok && v4.z > mv0) { mv0 = v4.z; mi0 = idx; }
        }
        {
          int idx = 4 * j + 3 - shift;
          bool ok = (idx >= 0) & (idx < 91);
          float ex = __expf(v4.w);
          e1 += ok ? ex : 0.f;
          if (ok && v4.w > mv1) { mv1 = v4.w; mi1 = idx; }
        }
      }
    } else {
      // last row: scalar loads, no over-read past the buffer
      const float* rp = logits + (size_t)row * 91;
      for (int j = 0; j < 91; ++j) {
        float v = rp[j];
        float ex = __expf(v);
        if (j & 1) { e1 += ex; if (v > mv1) { mv1 = v; mi1 = j; } }
        else       { e0 += ex; if (v > mv0) { mv0 = v; mi0 = j; } }
      }
    }
    float mv = mv0; int mi = mi0;
    if (mv1 > mv || (mv1 == mv && mi1 < mi)) { mv = mv1; mi = mi1; }
    float e = e0 + e1;
    float top1 = __expf(mv) / e;
    float4 rg = ((const float4*)reg)[row];
    float4 pp = ((const float4*)prop)[row];
    Box b = decode_clip(rg, pp, W, H);
    bool valid = (top1 > 0.05f) && ((b.x2 - b.x1) >= 0.01f) && ((b.y2 - b.y1) >= 0.01f);
    float sc = valid ? top1 : -1.f;
    scores[row] = sc;
    labels[row] = mi;
    if (sc > 0.f) {
      int bin = (int)(sc * (float)NBINS);
      if (bin > NBINS - 1) bin = NBINS - 1;
      atomicAdd(&lh[bin], 1u);
    }
  }
  __syncthreads();
  for (int i = t; i < NBINS; i += 256) {
    unsigned int cu = lh[i];
    if (cu) atomicAdd(&hist[i], cu);
  }
}

// K2: wave-shuffle suffix scan (2 barriers), then compaction.
__global__ __launch_bounds__(1024) void k2_compact(
    const float* __restrict__ scores, const unsigned int* __restrict__ hist,
    unsigned long long* __restrict__ cand, unsigned int* __restrict__ counter, int N) {
  __shared__ unsigned int wsum[16];
  __shared__ unsigned int wtail[16];
  __shared__ int bstar;
  const int t = threadIdx.x;
  const int lane = t & 63, w = t >> 6;
  const unsigned int h0 = hist[t];
  unsigned int v = h0;
  #pragma unroll
  for (int m = 1; m < 64; m <<= 1) {
    unsigned int o = __shfl_down(v, m, 64);
    if (lane + m < 64) v += o;
  }
  if (lane == 0) wsum[w] = v;
  if (t == 0) bstar = 0;
  __syncthreads();
  if (w == 0) {
    unsigned int u = (lane < 16) ? wsum[lane] : 0u;
    unsigned int inc = u;
    #pragma unroll
    for (int m = 1; m < 16; m <<= 1) {
      unsigned int o = __shfl_down(inc, m, 64);
      if (lane + m < 16) inc += o;
    }
    if (lane < 16) wtail[lane] = inc - u;
  }
  __syncthreads();
  unsigned int St = v + wtail[w];
  unsigned int St1 = St - h0;
  if (St >= TARGETC && St1 < TARGETC) {
    int b = t;
    if (St > CAPC) b = t + 1;
    if (b > NBINS - 1) b = NBINS - 1;
    bstar = b;
  }
  __syncthreads();
  const int bs = bstar;
  for (int i = blockIdx.x * blockDim.x + t; i < N; i += gridDim.x * blockDim.x) {
    float sc = scores[i];
    if (sc > 0.f) {
      int bin = (int)(sc * (float)NBINS);
      if (bin > NBINS - 1) bin = NBINS - 1;
      if (bin >= bs) {
        unsigned int pos = atomicAdd(counter, 1u);
        if (pos < CAPC) {
          unsigned long long key =
              ((unsigned long long)__float_as_uint(sc) << 32) |
              (unsigned long long)(0xFFFFFFFFu - (unsigned int)i);
          cand[pos] = key;
        }
      }
    }
  }
}

// K3: single block. bitonic sort over next-pow2(count), chunked greedy NMS, output.
__global__ __launch_bounds__(1024) void k3_nms(
    const unsigned long long* __restrict__ cand, const unsigned int* __restrict__ counter,
    const float* __restrict__ reg, const float* __restrict__ prop,
    const int* __restrict__ labels, const int* __restrict__ ph,
    const int* __restrict__ pw, float* __restrict__ out) {
  __shared__ unsigned long long keys[CAPC];
  __shared__ Box kbox[DET];
  __shared__ int klab[DET];
  __shared__ float kscore[DET];
  __shared__ Box cbox[64];
  __shared__ int clab[64];
  __shared__ float cscore[64];
  __shared__ unsigned int supk[64];
  __shared__ unsigned int rowm[64][2];
  __shared__ int nkept;
  const int t = threadIdx.x;
  unsigned int cnt_u = *counter;
  int count = (cnt_u < (unsigned int)CAPC) ? (int)cnt_u : CAPC;
  int P = 1;
  while (P < count) P <<= 1;
  if (P < 2) P = 2;
  for (int i = t; i < P; i += 1024) keys[i] = (i < count) ? cand[i] : 0ULL;
  if (t == 0) nkept = 0;
  __syncthreads();
  for (int k = 2; k <= P; k <<= 1) {
    for (int j = k >> 1; j > 0; j >>= 1) {
      for (int i = t; i < P; i += 1024) {
        int ixj = i ^ j;
        if (ixj > i) {
          unsigned long long a = keys[i], b = keys[ixj];
          bool sw = ((i & k) == 0) ? (a < b) : (a > b);
          if (sw) { keys[i] = b; keys[ixj] = a; }
        }
      }
      __syncthreads();
    }
  }
  const float W = scalar_to_float(pw), H = scalar_to_float(ph);
  for (int base = 0; base < count && nkept < DET; base += 64) {
    int nc = count - base; if (nc > 64) nc = 64;
    if (t < 64) { supk[t] = 0u; rowm[t][0] = 0u; rowm[t][1] = 0u; }
    if (t < nc) {
      unsigned long long key = keys[base + t];
      int row = (int)(0xFFFFFFFFu - (unsigned int)(key & 0xFFFFFFFFULL));
      cscore[t] = __uint_as_float((unsigned int)(key >> 32));
      clab[t] = labels[row];
      float4 r = ((const float4*)reg)[row];
      float4 p = ((const float4*)prop)[row];
      cbox[t] = decode_clip(r, p, W, H);
    }
    __syncthreads();
    int nk = nkept;
    {
      int c = t >> 4, kk = t & 15;
      if (c < nc) {
        unsigned int hit = 0u;
        for (int j = kk; j < nk; j += 16) {
          if (clab[c] == klab[j] && iou_f(cbox[c], kbox[j]) > 0.5f) { hit = 1u; break; }
        }
        if (hit) atomicOr(&supk[c], 1u);
      }
    }
    for (int p4 = t; p4 < 64 * 64; p4 += 1024) {
      int a = p4 >> 6, b = p4 & 63;
      if (a < b && b < nc) {
        if (clab[a] == clab[b] && iou_f(cbox[a], cbox[b]) > 0.5f)
          atomicOr(&rowm[a][b >> 5], 1u << (b & 31));
      }
    }
    __syncthreads();
    if (t == 0) {
      unsigned int s0 = 0u, s1 = 0u;
      int nkl = nkept;
      for (int j = 0; j < nc && nkl < DET; ++j) {
        unsigned int bit = (j < 32) ? ((s0 >> j) & 1u) : ((s1 >> (j - 32)) & 1u);
        if (!supk[j] && !bit) {
          kbox[nkl] = cbox[j];
          klab[nkl] = clab[j];
          kscore[nkl] = cscore[j];
          ++nkl;
          s0 |= rowm[j][0];
          s1 |= rowm[j][1];
        }
      }
      nkept = nkl;
    }
    __syncthreads();
  }
  int nk = nkept;
  if (t < DET) {
    bool v = t < nk;
    Box b = v ? kbox[t] : Box{0.f, 0.f, 0.f, 0.f};
    out[t * 4 + 0] = b.x1;
    out[t * 4 + 1] = b.y1;
    out[t * 4 + 2] = b.x2;
    out[t * 4 + 3] = b.y2;
    out[400 + t] = v ? kscore[t] : 0.f;
    out[500 + t] = v ? (float)klab[t] : -1.f;
  }
}

extern "C" void kernel_launch(void* const* d_in, const int* in_sizes, int n_in,
                              void* d_out, int out_size, void* d_ws, size_t ws_size,
                              hipStream_t stream) {
  const float* logits = (const float*)d_in[0];
  const float* reg    = (const float*)d_in[1];
  const float* prop   = (const float*)d_in[2];
  const int*   ph     = (const int*)d_in[3];
  const int*   pw     = (const int*)d_in[4];
  float* out = (float*)d_out;

  const int N = in_sizes[1] / 4;

  char* ws = (char*)d_ws;
  float* scores = (float*)ws;                                  // N f32
  int* labels   = (int*)(ws + (size_t)N * 4);                  // N i32
  size_t off = (size_t)N * 8;
  off = (off + 255) & ~(size_t)255;
  unsigned int* hist = (unsigned int*)(ws + off);              // NBINS u32
  unsigned int* counter = hist + NBINS;                        // 1 u32
  unsigned long long* cand = (unsigned long long*)(ws + off + NBINS * 4 + 64); // CAPC u64

  k0_zero<<<(NBINS + 16 + 255) / 256, 256, 0, stream>>>(hist);
  k1_score<<<(N + 255) / 256, 256, 0, stream>>>(logits, reg, prop, ph, pw, scores, labels, hist, N);
  k2_compact<<<256, 1024, 0, stream>>>(scores, hist, cand, counter, N);
  k3_nms<<<1, 1024, 0, stream>>>(cand, counter, reg, prop, labels, ph, pw, out);
}

// Round 10
// 66.860 us; speedup vs baseline: 1.2523x; 1.1915x over previous
//
#include <hip/hip_runtime.h>

#define NBINS   1024
#define CAPC    4096
#define TARGETC 256
#define DET     100
#define XCLIP   4.135166556742356f
#define CHUNK   32
#define TILE4   768    // float4 slots per buffer: 728 used + pad for clamped lanes

__device__ inline float scalar_to_float(const int* p) {
  int v = *p;
  return (v >= 0 && v < (1 << 20)) ? (float)v : __int_as_float(v);
}

struct Box { float x1, y1, x2, y2; };

__device__ inline Box decode_clip(float4 r, float4 p, float W, float H) {
  float w = p.z - p.x, h = p.w - p.y;
  float cx = p.x + 0.5f * w, cy = p.y + 0.5f * h;
  float dx = r.x / 10.f, dy = r.y / 10.f;
  float dw = fminf(r.z / 5.f, XCLIP), dh = fminf(r.w / 5.f, XCLIP);
  float pcx = dx * w + cx, pcy = dy * h + cy;
  float pw = __expf(dw) * w, ph = __expf(dh) * h;
  Box b;
  b.x1 = fminf(fmaxf(pcx - 0.5f * pw, 0.f), W);
  b.y1 = fminf(fmaxf(pcy - 0.5f * ph, 0.f), H);
  b.x2 = fminf(fmaxf(pcx + 0.5f * pw, 0.f), W);
  b.y2 = fminf(fmaxf(pcy + 0.5f * ph, 0.f), H);
  return b;
}

__device__ inline float iou_f(const Box& a, const Box& b) {
  float area1 = (a.x2 - a.x1) * (a.y2 - a.y1);
  float area2 = (b.x2 - b.x1) * (b.y2 - b.y1);
  float lx = fmaxf(a.x1, b.x1), ly = fmaxf(a.y1, b.y1);
  float rx = fminf(a.x2, b.x2), ry = fminf(a.y2, b.y2);
  float w = fmaxf(rx - lx, 0.f), h = fmaxf(ry - ly, 0.f);
  float inter = w * h;
  return inter / (area1 + area2 - inter);
}

// K0: zero hist + counter.
__global__ __launch_bounds__(256) void k0_zero(unsigned int* __restrict__ hist) {
  int t = blockIdx.x * 256 + threadIdx.x;
  if (t < NBINS + 16) hist[t] = 0u;
}

// K1 v10: R7 skeleton (global_load_lds double-buffer, stage-next-before-compute)
// with 2x the wave concurrency: CHUNK=32 rows -> 24.6KB LDS -> 6 blocks/CU,
// grid 1536 -> 24 waves/CU. Histogram removed entirely (moved to k2a): no
// hist LDS, no init/flush barriers, no atomics in k1.
__global__ __launch_bounds__(256) void k1_score(
    const float* __restrict__ logits, const float* __restrict__ reg,
    const float* __restrict__ prop, const int* __restrict__ ph,
    const int* __restrict__ pw, float* __restrict__ scores,
    int* __restrict__ labels, int N) {
  __shared__ float4 tile[2][TILE4];       // 24576 B
  const int t = threadIdx.x, wv = t >> 6, lane = t & 63;
  const float W = scalar_to_float(pw), H = scalar_to_float(ph);
  const int nchunks = (N + CHUNK - 1) / CHUNK;

  auto stage = [&](int cc, int b) {
    const int rows = min(CHUNK, N - cc * CHUNK);
    const int nf = rows * 91, nf4 = nf >> 2;
    const float4* s4 = (const float4*)(logits + (size_t)cc * CHUNK * 91);
    float4* dst = &tile[b][0];
    #pragma unroll
    for (int k = 0; k < 3; ++k) {
      int b4 = (wv * 3 + k) << 6;         // wave-uniform LDS slot base
      if (b4 < nf4) {
        int g = b4 + lane;
        if (g > nf4 - 1) g = nf4 - 1;     // clamped dup reads; LDS dest in pad
        __builtin_amdgcn_global_load_lds(
            (const __attribute__((address_space(1))) void*)(s4 + g),
            (__attribute__((address_space(3))) void*)(dst + b4),
            16, 0, 0);
      }
    }
    for (int i = (nf4 << 2) + t; i < nf; i += 256)   // generic-N tail only
      ((float*)dst)[i] = logits[(size_t)cc * CHUNK * 91 + i];
  };

  int c = blockIdx.x;
  int cur = 0;
  if (c < nchunks) stage(c, 0);
  __syncthreads();
  while (c < nchunks) {
    const int cn = c + gridDim.x;
    if (cn < nchunks) stage(cn, cur ^ 1);  // in flight during compute below
    const int rows = min(CHUNK, N - c * CHUNK);
    const int r = t >> 3, s = t & 7;
    if (r < rows) {
      const float* rowp = (const float*)&tile[cur][0] + r * 91;
      float mv = -3.402823466e38f; int mi = 1 << 20;
      float e0 = 0.f, e1 = 0.f;
      #pragma unroll
      for (int k = 0; k < 12; ++k) {
        int j = s + (k << 3);
        if (j < 91) {
          float v = rowp[j];
          float ex = __expf(v);
          if (k & 1) e1 += ex; else e0 += ex;
          if (v > mv) { mv = v; mi = j; }
        }
      }
      float e = e0 + e1;
      #pragma unroll
      for (int m = 1; m <= 4; m <<= 1) {
        float ov = __shfl_xor(mv, m, 64);
        int   oi = __shfl_xor(mi, m, 64);
        float oe = __shfl_xor(e, m, 64);
        e += oe;
        if (ov > mv || (ov == mv && oi < mi)) { mv = ov; mi = oi; }
      }
      if (s == 0) {
        float top1 = __expf(mv) / e;
        const int row = c * CHUNK + r;
        float4 rg = ((const float4*)reg)[row];
        float4 pp = ((const float4*)prop)[row];
        Box b = decode_clip(rg, pp, W, H);
        bool valid = (top1 > 0.05f) && ((b.x2 - b.x1) >= 0.01f) && ((b.y2 - b.y1) >= 0.01f);
        float sc = valid ? top1 : -1.f;
        scores[row] = sc;
        labels[row] = mi;
      }
    }
    __syncthreads();   // drains staging vmcnt AFTER compute
    cur ^= 1;
    c = cn;
  }
}

// K2a: build global histogram from scores (LDS hist per block, 128 blocks).
__global__ __launch_bounds__(1024) void k2a_hist(
    const float* __restrict__ scores, unsigned int* __restrict__ hist, int N) {
  __shared__ unsigned int lh[NBINS];
  const int t = threadIdx.x;
  lh[t] = 0u;
  __syncthreads();
  for (int i = blockIdx.x * 1024 + t; i < N; i += gridDim.x * 1024) {
    float sc = scores[i];
    if (sc > 0.f) {
      int bin = (int)(sc * (float)NBINS);
      if (bin > NBINS - 1) bin = NBINS - 1;
      atomicAdd(&lh[bin], 1u);
    }
  }
  __syncthreads();
  unsigned int cu = lh[t];
  if (cu) atomicAdd(&hist[t], cu);
}

// K2b: cutoff from hist (wave-shuffle suffix scan), then compaction.
__global__ __launch_bounds__(1024) void k2_compact(
    const float* __restrict__ scores, const unsigned int* __restrict__ hist,
    unsigned long long* __restrict__ cand, unsigned int* __restrict__ counter, int N) {
  __shared__ unsigned int wsum[16];
  __shared__ unsigned int wtail[16];
  __shared__ int bstar;
  const int t = threadIdx.x;
  const int lane = t & 63, w = t >> 6;
  const unsigned int h0 = hist[t];
  unsigned int v = h0;
  #pragma unroll
  for (int m = 1; m < 64; m <<= 1) {
    unsigned int o = __shfl_down(v, m, 64);
    if (lane + m < 64) v += o;
  }
  if (lane == 0) wsum[w] = v;
  if (t == 0) bstar = 0;
  __syncthreads();
  if (w == 0) {
    unsigned int u = (lane < 16) ? wsum[lane] : 0u;
    unsigned int inc = u;
    #pragma unroll
    for (int m = 1; m < 16; m <<= 1) {
      unsigned int o = __shfl_down(inc, m, 64);
      if (lane + m < 16) inc += o;
    }
    if (lane < 16) wtail[lane] = inc - u;
  }
  __syncthreads();
  unsigned int St = v + wtail[w];
  unsigned int St1 = St - h0;
  if (St >= TARGETC && St1 < TARGETC) {
    int b = t;
    if (St > CAPC) b = t + 1;
    if (b > NBINS - 1) b = NBINS - 1;
    bstar = b;
  }
  __syncthreads();
  const int bs = bstar;
  for (int i = blockIdx.x * blockDim.x + t; i < N; i += gridDim.x * blockDim.x) {
    float sc = scores[i];
    if (sc > 0.f) {
      int bin = (int)(sc * (float)NBINS);
      if (bin > NBINS - 1) bin = NBINS - 1;
      if (bin >= bs) {
        unsigned int pos = atomicAdd(counter, 1u);
        if (pos < CAPC) {
          unsigned long long key =
              ((unsigned long long)__float_as_uint(sc) << 32) |
              (unsigned long long)(0xFFFFFFFFu - (unsigned int)i);
          cand[pos] = key;
        }
      }
    }
  }
}

// K3: single block. bitonic sort over next-pow2(count), chunked greedy NMS, output.
__global__ __launch_bounds__(1024) void k3_nms(
    const unsigned long long* __restrict__ cand, const unsigned int* __restrict__ counter,
    const float* __restrict__ reg, const float* __restrict__ prop,
    const int* __restrict__ labels, const int* __restrict__ ph,
    const int* __restrict__ pw, float* __restrict__ out) {
  __shared__ unsigned long long keys[CAPC];
  __shared__ Box kbox[DET];
  __shared__ int klab[DET];
  __shared__ float kscore[DET];
  __shared__ Box cbox[64];
  __shared__ int clab[64];
  __shared__ float cscore[64];
  __shared__ unsigned int supk[64];
  __shared__ unsigned int rowm[64][2];
  __shared__ int nkept;
  const int t = threadIdx.x;
  unsigned int cnt_u = *counter;
  int count = (cnt_u < (unsigned int)CAPC) ? (int)cnt_u : CAPC;
  int P = 1;
  while (P < count) P <<= 1;
  if (P < 2) P = 2;
  for (int i = t; i < P; i += 1024) keys[i] = (i < count) ? cand[i] : 0ULL;
  if (t == 0) nkept = 0;
  __syncthreads();
  for (int k = 2; k <= P; k <<= 1) {
    for (int j = k >> 1; j > 0; j >>= 1) {
      for (int i = t; i < P; i += 1024) {
        int ixj = i ^ j;
        if (ixj > i) {
          unsigned long long a = keys[i], b = keys[ixj];
          bool sw = ((i & k) == 0) ? (a < b) : (a > b);
          if (sw) { keys[i] = b; keys[ixj] = a; }
        }
      }
      __syncthreads();
    }
  }
  const float W = scalar_to_float(pw), H = scalar_to_float(ph);
  for (int base = 0; base < count && nkept < DET; base += 64) {
    int nc = count - base; if (nc > 64) nc = 64;
    if (t < 64) { supk[t] = 0u; rowm[t][0] = 0u; rowm[t][1] = 0u; }
    if (t < nc) {
      unsigned long long key = keys[base + t];
      int row = (int)(0xFFFFFFFFu - (unsigned int)(key & 0xFFFFFFFFULL));
      cscore[t] = __uint_as_float((unsigned int)(key >> 32));
      clab[t] = labels[row];
      float4 r = ((const float4*)reg)[row];
      float4 p = ((const float4*)prop)[row];
      cbox[t] = decode_clip(r, p, W, H);
    }
    __syncthreads();
    int nk = nkept;
    {
      int c = t >> 4, kk = t & 15;
      if (c < nc) {
        unsigned int hit = 0u;
        for (int j = kk; j < nk; j += 16) {
          if (clab[c] == klab[j] && iou_f(cbox[c], kbox[j]) > 0.5f) { hit = 1u; break; }
        }
        if (hit) atomicOr(&supk[c], 1u);
      }
    }
    for (int p4 = t; p4 < 64 * 64; p4 += 1024) {
      int a = p4 >> 6, b = p4 & 63;
      if (a < b && b < nc) {
        if (clab[a] == clab[b] && iou_f(cbox[a], cbox[b]) > 0.5f)
          atomicOr(&rowm[a][b >> 5], 1u << (b & 31));
      }
    }
    __syncthreads();
    if (t == 0) {
      unsigned int s0 = 0u, s1 = 0u;
      int nkl = nkept;
      for (int j = 0; j < nc && nkl < DET; ++j) {
        unsigned int bit = (j < 32) ? ((s0 >> j) & 1u) : ((s1 >> (j - 32)) & 1u);
        if (!supk[j] && !bit) {
          kbox[nkl] = cbox[j];
          klab[nkl] = clab[j];
          kscore[nkl] = cscore[j];
          ++nkl;
          s0 |= rowm[j][0];
          s1 |= rowm[j][1];
        }
      }
      nkept = nkl;
    }
    __syncthreads();
  }
  int nk = nkept;
  if (t < DET) {
    bool v = t < nk;
    Box b = v ? kbox[t] : Box{0.f, 0.f, 0.f, 0.f};
    out[t * 4 + 0] = b.x1;
    out[t * 4 + 1] = b.y1;
    out[t * 4 + 2] = b.x2;
    out[t * 4 + 3] = b.y2;
    out[400 + t] = v ? kscore[t] : 0.f;
    out[500 + t] = v ? (float)klab[t] : -1.f;
  }
}

extern "C" void kernel_launch(void* const* d_in, const int* in_sizes, int n_in,
                              void* d_out, int out_size, void* d_ws, size_t ws_size,
                              hipStream_t stream) {
  const float* logits = (const float*)d_in[0];
  const float* reg    = (const float*)d_in[1];
  const float* prop   = (const float*)d_in[2];
  const int*   ph     = (const int*)d_in[3];
  const int*   pw     = (const int*)d_in[4];
  float* out = (float*)d_out;

  const int N = in_sizes[1] / 4;

  char* ws = (char*)d_ws;
  float* scores = (float*)ws;                                  // N f32
  int* labels   = (int*)(ws + (size_t)N * 4);                  // N i32
  size_t off = (size_t)N * 8;
  off = (off + 255) & ~(size_t)255;
  unsigned int* hist = (unsigned int*)(ws + off);              // NBINS u32
  unsigned int* counter = hist + NBINS;                        // 1 u32
  unsigned long long* cand = (unsigned long long*)(ws + off + NBINS * 4 + 64); // CAPC u64

  k0_zero<<<(NBINS + 16 + 255) / 256, 256, 0, stream>>>(hist);
  k1_score<<<1536, 256, 0, stream>>>(logits, reg, prop, ph, pw, scores, labels, N);
  k2a_hist<<<128, 1024, 0, stream>>>(scores, hist, N);
  k2_compact<<<128, 1024, 0, stream>>>(scores, hist, cand, counter, N);
  k3_nms<<<1, 1024, 0, stream>>>(cand, counter, reg, prop, labels, ph, pw, out);
}

// Round 11
// 63.212 us; speedup vs baseline: 1.3246x; 1.0577x over previous
//
#include <hip/hip_runtime.h>

#define NBINS   1024
#define CAPC    4096
#define TARGETC 256
#define DET     100
#define XCLIP   4.135166556742356f
#define CHUNK   24
#define TILE4   576    // 546 used float4 slots + clamp pad
#define NPART   64     // k2a partial-histogram blocks

__device__ inline float scalar_to_float(const int* p) {
  int v = *p;
  return (v >= 0 && v < (1 << 20)) ? (float)v : __int_as_float(v);
}

struct Box { float x1, y1, x2, y2; };

__device__ inline Box decode_clip(float4 r, float4 p, float W, float H) {
  float w = p.z - p.x, h = p.w - p.y;
  float cx = p.x + 0.5f * w, cy = p.y + 0.5f * h;
  float dx = r.x / 10.f, dy = r.y / 10.f;
  float dw = fminf(r.z / 5.f, XCLIP), dh = fminf(r.w / 5.f, XCLIP);
  float pcx = dx * w + cx, pcy = dy * h + cy;
  float pw = __expf(dw) * w, ph = __expf(dh) * h;
  Box b;
  b.x1 = fminf(fmaxf(pcx - 0.5f * pw, 0.f), W);
  b.y1 = fminf(fmaxf(pcy - 0.5f * ph, 0.f), H);
  b.x2 = fminf(fmaxf(pcx + 0.5f * pw, 0.f), W);
  b.y2 = fminf(fmaxf(pcy + 0.5f * ph, 0.f), H);
  return b;
}

__device__ inline float iou_f(const Box& a, const Box& b) {
  float area1 = (a.x2 - a.x1) * (a.y2 - a.y1);
  float area2 = (b.x2 - b.x1) * (b.y2 - b.y1);
  float lx = fmaxf(a.x1, b.x1), ly = fmaxf(a.y1, b.y1);
  float rx = fminf(a.x2, b.x2), ry = fminf(a.y2, b.y2);
  float w = fmaxf(rx - lx, 0.f), h = fmaxf(ry - ly, 0.f);
  float inter = w * h;
  return inter / (area1 + area2 - inter);
}

// K1 v11: global_load_lds double-buffer at max occupancy. CHUNK=24 rows ->
// 18.4KB LDS -> 8 blocks/CU -> 32 waves/CU (the HW cap). Load slots striped
// L = wv + 4k so every wave issues DMA. No hist work in k1.
__global__ __launch_bounds__(256) void k1_score(
    const float* __restrict__ logits, const float* __restrict__ reg,
    const float* __restrict__ prop, const int* __restrict__ ph,
    const int* __restrict__ pw, float* __restrict__ scores,
    int* __restrict__ labels, int N) {
  __shared__ float4 tile[2][TILE4];       // 18432 B
  const int t = threadIdx.x, wv = t >> 6, lane = t & 63;
  const float W = scalar_to_float(pw), H = scalar_to_float(ph);
  const int nchunks = (N + CHUNK - 1) / CHUNK;

  auto stage = [&](int cc, int b) {
    const int rows = min(CHUNK, N - cc * CHUNK);
    const int nf = rows * 91, nf4 = nf >> 2;
    const float4* s4 = (const float4*)(logits + (size_t)cc * CHUNK * 91);
    float4* dst = &tile[b][0];
    #pragma unroll
    for (int k = 0; k < 3; ++k) {
      int b4 = (wv + (k << 2)) << 6;      // load L = wv+4k, wave-uniform base
      if (b4 < nf4) {
        int g = b4 + lane;
        if (g > nf4 - 1) g = nf4 - 1;     // clamped dups land in pad slots
        __builtin_amdgcn_global_load_lds(
            (const __attribute__((address_space(1))) void*)(s4 + g),
            (__attribute__((address_space(3))) void*)(dst + b4),
            16, 0, 0);
      }
    }
    for (int i = (nf4 << 2) + t; i < nf; i += 256)   // generic-N tail only
      ((float*)dst)[i] = logits[(size_t)cc * CHUNK * 91 + i];
  };

  int c = blockIdx.x;
  int cur = 0;
  if (c < nchunks) stage(c, 0);
  __syncthreads();
  while (c < nchunks) {
    const int cn = c + gridDim.x;
    if (cn < nchunks) stage(cn, cur ^ 1);  // in flight during compute below
    const int rows = min(CHUNK, N - c * CHUNK);
    const int r = t >> 3, s = t & 7;
    if (r < rows) {
      const float* rowp = (const float*)&tile[cur][0] + r * 91;
      float mv = -3.402823466e38f; int mi = 1 << 20;
      float e0 = 0.f, e1 = 0.f;
      #pragma unroll
      for (int k = 0; k < 12; ++k) {
        int j = s + (k << 3);
        if (j < 91) {
          float v = rowp[j];
          float ex = __expf(v);
          if (k & 1) e1 += ex; else e0 += ex;
          if (v > mv) { mv = v; mi = j; }
        }
      }
      float e = e0 + e1;
      #pragma unroll
      for (int m = 1; m <= 4; m <<= 1) {
        float ov = __shfl_xor(mv, m, 64);
        int   oi = __shfl_xor(mi, m, 64);
        float oe = __shfl_xor(e, m, 64);
        e += oe;
        if (ov > mv || (ov == mv && oi < mi)) { mv = ov; mi = oi; }
      }
      if (s == 0) {
        float top1 = __expf(mv) / e;
        const int row = c * CHUNK + r;
        float4 rg = ((const float4*)reg)[row];
        float4 pp = ((const float4*)prop)[row];
        Box b = decode_clip(rg, pp, W, H);
        bool valid = (top1 > 0.05f) && ((b.x2 - b.x1) >= 0.01f) && ((b.y2 - b.y1) >= 0.01f);
        float sc = valid ? top1 : -1.f;
        scores[row] = sc;
        labels[row] = mi;
      }
    }
    __syncthreads();   // drains staging vmcnt AFTER compute
    cur ^= 1;
    c = cn;
  }
}

// K2a: per-block histogram partials (no global atomics) + zero the counter.
__global__ __launch_bounds__(1024) void k2a_hist(
    const float* __restrict__ scores, unsigned int* __restrict__ histp,
    unsigned int* __restrict__ counter, int N) {
  __shared__ unsigned int lh[NBINS];
  const int t = threadIdx.x;
  lh[t] = 0u;
  if (blockIdx.x == 0 && t == 0) *counter = 0u;
  __syncthreads();
  for (int i = blockIdx.x * 1024 + t; i < N; i += gridDim.x * 1024) {
    float sc = scores[i];
    if (sc > 0.f) {
      int bin = (int)(sc * (float)NBINS);
      if (bin > NBINS - 1) bin = NBINS - 1;
      atomicAdd(&lh[bin], 1u);
    }
  }
  __syncthreads();
  histp[blockIdx.x * NBINS + t] = lh[t];
}

// K2b: sum partials -> suffix scan -> cutoff -> compaction.
__global__ __launch_bounds__(1024) void k2_compact(
    const float* __restrict__ scores, const unsigned int* __restrict__ histp,
    unsigned long long* __restrict__ cand, unsigned int* __restrict__ counter, int N) {
  __shared__ unsigned int wsum[16];
  __shared__ unsigned int wtail[16];
  __shared__ int bstar;
  const int t = threadIdx.x;
  const int lane = t & 63, w = t >> 6;
  unsigned int h0 = 0u;
  #pragma unroll 8
  for (int b = 0; b < NPART; ++b) h0 += histp[b * NBINS + t];
  unsigned int v = h0;
  #pragma unroll
  for (int m = 1; m < 64; m <<= 1) {
    unsigned int o = __shfl_down(v, m, 64);
    if (lane + m < 64) v += o;
  }
  if (lane == 0) wsum[w] = v;
  if (t == 0) bstar = 0;
  __syncthreads();
  if (w == 0) {
    unsigned int u = (lane < 16) ? wsum[lane] : 0u;
    unsigned int inc = u;
    #pragma unroll
    for (int m = 1; m < 16; m <<= 1) {
      unsigned int o = __shfl_down(inc, m, 64);
      if (lane + m < 16) inc += o;
    }
    if (lane < 16) wtail[lane] = inc - u;
  }
  __syncthreads();
  unsigned int St = v + wtail[w];
  unsigned int St1 = St - h0;
  if (St >= TARGETC && St1 < TARGETC) {
    int b = t;
    if (St > CAPC) b = t + 1;
    if (b > NBINS - 1) b = NBINS - 1;
    bstar = b;
  }
  __syncthreads();
  const int bs = bstar;
  for (int i = blockIdx.x * blockDim.x + t; i < N; i += gridDim.x * blockDim.x) {
    float sc = scores[i];
    if (sc > 0.f) {
      int bin = (int)(sc * (float)NBINS);
      if (bin > NBINS - 1) bin = NBINS - 1;
      if (bin >= bs) {
        unsigned int pos = atomicAdd(counter, 1u);
        if (pos < CAPC) {
          unsigned long long key =
              ((unsigned long long)__float_as_uint(sc) << 32) |
              (unsigned long long)(0xFFFFFFFFu - (unsigned int)i);
          cand[pos] = key;
        }
      }
    }
  }
}

// K3: single block. bitonic sort over next-pow2(count), chunked greedy NMS, output.
__global__ __launch_bounds__(1024) void k3_nms(
    const unsigned long long* __restrict__ cand, const unsigned int* __restrict__ counter,
    const float* __restrict__ reg, const float* __restrict__ prop,
    const int* __restrict__ labels, const int* __restrict__ ph,
    const int* __restrict__ pw, float* __restrict__ out) {
  __shared__ unsigned long long keys[CAPC];
  __shared__ Box kbox[DET];
  __shared__ int klab[DET];
  __shared__ float kscore[DET];
  __shared__ Box cbox[64];
  __shared__ int clab[64];
  __shared__ float cscore[64];
  __shared__ unsigned int supk[64];
  __shared__ unsigned int rowm[64][2];
  __shared__ int nkept;
  const int t = threadIdx.x;
  unsigned int cnt_u = *counter;
  int count = (cnt_u < (unsigned int)CAPC) ? (int)cnt_u : CAPC;
  int P = 1;
  while (P < count) P <<= 1;
  if (P < 2) P = 2;
  for (int i = t; i < P; i += 1024) keys[i] = (i < count) ? cand[i] : 0ULL;
  if (t == 0) nkept = 0;
  __syncthreads();
  for (int k = 2; k <= P; k <<= 1) {
    for (int j = k >> 1; j > 0; j >>= 1) {
      for (int i = t; i < P; i += 1024) {
        int ixj = i ^ j;
        if (ixj > i) {
          unsigned long long a = keys[i], b = keys[ixj];
          bool sw = ((i & k) == 0) ? (a < b) : (a > b);
          if (sw) { keys[i] = b; keys[ixj] = a; }
        }
      }
      __syncthreads();
    }
  }
  const float W = scalar_to_float(pw), H = scalar_to_float(ph);
  for (int base = 0; base < count && nkept < DET; base += 64) {
    int nc = count - base; if (nc > 64) nc = 64;
    if (t < 64) { supk[t] = 0u; rowm[t][0] = 0u; rowm[t][1] = 0u; }
    if (t < nc) {
      unsigned long long key = keys[base + t];
      int row = (int)(0xFFFFFFFFu - (unsigned int)(key & 0xFFFFFFFFULL));
      cscore[t] = __uint_as_float((unsigned int)(key >> 32));
      clab[t] = labels[row];
      float4 r = ((const float4*)reg)[row];
      float4 p = ((const float4*)prop)[row];
      cbox[t] = decode_clip(r, p, W, H);
    }
    __syncthreads();
    int nk = nkept;
    {
      int c = t >> 4, kk = t & 15;
      if (c < nc) {
        unsigned int hit = 0u;
        for (int j = kk; j < nk; j += 16) {
          if (clab[c] == klab[j] && iou_f(cbox[c], kbox[j]) > 0.5f) { hit = 1u; break; }
        }
        if (hit) atomicOr(&supk[c], 1u);
      }
    }
    for (int p4 = t; p4 < 64 * 64; p4 += 1024) {
      int a = p4 >> 6, b = p4 & 63;
      if (a < b && b < nc) {
        if (clab[a] == clab[b] && iou_f(cbox[a], cbox[b]) > 0.5f)
          atomicOr(&rowm[a][b >> 5], 1u << (b & 31));
      }
    }
    __syncthreads();
    if (t == 0) {
      unsigned int s0 = 0u, s1 = 0u;
      int nkl = nkept;
      for (int j = 0; j < nc && nkl < DET; ++j) {
        unsigned int bit = (j < 32) ? ((s0 >> j) & 1u) : ((s1 >> (j - 32)) & 1u);
        if (!supk[j] && !bit) {
          kbox[nkl] = cbox[j];
          klab[nkl] = clab[j];
          kscore[nkl] = cscore[j];
          ++nkl;
          s0 |= rowm[j][0];
          s1 |= rowm[j][1];
        }
      }
      nkept = nkl;
    }
    __syncthreads();
  }
  int nk = nkept;
  if (t < DET) {
    bool v = t < nk;
    Box b = v ? kbox[t] : Box{0.f, 0.f, 0.f, 0.f};
    out[t * 4 + 0] = b.x1;
    out[t * 4 + 1] = b.y1;
    out[t * 4 + 2] = b.x2;
    out[t * 4 + 3] = b.y2;
    out[400 + t] = v ? kscore[t] : 0.f;
    out[500 + t] = v ? (float)klab[t] : -1.f;
  }
}

extern "C" void kernel_launch(void* const* d_in, const int* in_sizes, int n_in,
                              void* d_out, int out_size, void* d_ws, size_t ws_size,
                              hipStream_t stream) {
  const float* logits = (const float*)d_in[0];
  const float* reg    = (const float*)d_in[1];
  const float* prop   = (const float*)d_in[2];
  const int*   ph     = (const int*)d_in[3];
  const int*   pw     = (const int*)d_in[4];
  float* out = (float*)d_out;

  const int N = in_sizes[1] / 4;

  char* ws = (char*)d_ws;
  float* scores = (float*)ws;                                  // N f32
  int* labels   = (int*)(ws + (size_t)N * 4);                  // N i32
  size_t off = (size_t)N * 8;
  off = (off + 255) & ~(size_t)255;
  unsigned int* histp = (unsigned int*)(ws + off);             // NPART*NBINS u32
  unsigned int* counter = histp + NPART * NBINS;               // 1 u32
  unsigned long long* cand =
      (unsigned long long*)(ws + off + (size_t)NPART * NBINS * 4 + 64); // CAPC u64

  k1_score<<<2048, 256, 0, stream>>>(logits, reg, prop, ph, pw, scores, labels, N);
  k2a_hist<<<NPART, 1024, 0, stream>>>(scores, histp, counter, N);
  k2_compact<<<128, 1024, 0, stream>>>(scores, histp, cand, counter, N);
  k3_nms<<<1, 1024, 0, stream>>>(cand, counter, reg, prop, labels, ph, pw, out);
}